// Round 1
// baseline (1381.457 us; speedup 1.0000x reference)
//
#include <hip/hip_runtime.h>
#include <math.h>

// ---------------------------------------------------------------------------
// MultiReferenceWindowAttention, all-f32 baseline.
// B_=128, T=4, M=4, N=64, C=192, nH=6, hd=32, BT=512, nW=64
// Workspace layout (bytes):
//   [0, 1179648)            : 7 transposed weight matrices
//   A0 = 1179648            : qbuf (25165824)  -> later t0 -> later opo
//   A1 = A0 + 25165824      : kbuf            -> later qq
//   A2 = A1 + 25165824      : vbuf            -> later opool
//   A3 = A2 + 25165824      : xp (100663296)
// total = 177340416 bytes (~169.1 MiB)
// ---------------------------------------------------------------------------

// ---- weight transpose: w (rows x 192) -> wT (192 x rows) ----
__global__ void wt_kernel(const float* __restrict__ w, float* __restrict__ wT, int rows) {
    int i = blockIdx.x * blockDim.x + threadIdx.x;
    if (i >= rows * 192) return;
    int r = i / 192, c = i - r * 192;
    wT[c * rows + r] = w[i];
}

// ---- GEMM: C[m, oc] = sum_k A[m,k] * WT[k,oc] + bias[oc]
// M fixed 32768 tokens, K=192. tile 128m x 96oc, K chunk 64.
// EPI: 0 = plain, 1 = exact gelu, 2 = kv split (oc<192 -> C0, else C1)
template <int EPI>
__global__ __launch_bounds__(256, 2)
void gemm_kernel(const float* __restrict__ A, const float* __restrict__ WT,
                 const float* __restrict__ bias, float* __restrict__ C0,
                 float* __restrict__ C1, int Nout)
{
    __shared__ float As[64 * 128];   // [k][m], column XOR-swizzled by (k&31)
    __shared__ float Ws[64 * 96];    // [k][n]
    const int tid = threadIdx.x;
    const int gm0 = blockIdx.x * 128;
    const int gn0 = blockIdx.y * 96;
    const int m0 = (tid >> 4) * 8;   // 8 tokens per thread
    const int n0 = (tid & 15) * 6;   // 6 out-channels per thread

    float acc[8][6];
#pragma unroll
    for (int i = 0; i < 8; i++)
#pragma unroll
        for (int j = 0; j < 6; j++) acc[i][j] = 0.f;

    for (int kb = 0; kb < 192; kb += 64) {
        // stage A tile 128 x 64 (transposed into [k][m] with XOR swizzle)
#pragma unroll
        for (int j = 0; j < 8; j++) {
            int f4 = tid + j * 256;          // 0..2047 float4s
            int r = f4 >> 4;                 // token row 0..127
            int c4 = (f4 & 15) << 2;         // k 0..60
            float4 av = *reinterpret_cast<const float4*>(&A[(gm0 + r) * 192 + kb + c4]);
            float vals[4] = {av.x, av.y, av.z, av.w};
#pragma unroll
            for (int jj = 0; jj < 4; jj++) {
                int k = c4 + jj;
                As[k * 128 + (r ^ (k & 31))] = vals[jj];
            }
        }
        // stage W tile 64 x 96
#pragma unroll
        for (int j = 0; j < 24; j++) {
            int f = tid + j * 256;           // 0..6143
            int kk = f / 96;
            int nn = f - kk * 96;
            Ws[f] = WT[(kb + kk) * Nout + gn0 + nn];
        }
        __syncthreads();

        for (int kk8 = 0; kk8 < 64; kk8 += 8) {
#pragma unroll
            for (int kk = 0; kk < 8; kk++) {
                int k = kk8 + kk;
                int colbase = m0 ^ (k & 24);
                float4 a0 = *reinterpret_cast<const float4*>(&As[k * 128 + colbase]);
                float4 a1 = *reinterpret_cast<const float4*>(&As[k * 128 + colbase + 4]);
                float av8[8] = {a0.x, a0.y, a0.z, a0.w, a1.x, a1.y, a1.z, a1.w};
                float2 w0 = *reinterpret_cast<const float2*>(&Ws[k * 96 + n0]);
                float2 w1 = *reinterpret_cast<const float2*>(&Ws[k * 96 + n0 + 2]);
                float2 w2 = *reinterpret_cast<const float2*>(&Ws[k * 96 + n0 + 4]);
                float wv[6] = {w0.x, w0.y, w1.x, w1.y, w2.x, w2.y};
#pragma unroll
                for (int j = 0; j < 8; j++) {
                    float a = av8[j];
#pragma unroll
                    for (int n = 0; n < 6; n++) acc[j ^ kk][n] += a * wv[n];  // j^kk compile-time
                }
            }
        }
        __syncthreads();
    }

    float bv[6];
#pragma unroll
    for (int n = 0; n < 6; n++) bv[n] = bias[gn0 + n0 + n];

    float* dst = C0;
    int ocb = gn0 + n0;
    if (EPI == 2) {
        if (gn0 >= 192) { dst = C1; ocb -= 192; }
    }
#pragma unroll
    for (int i = 0; i < 8; i++) {
        int m = gm0 + m0 + i;
#pragma unroll
        for (int n = 0; n < 6; n++) {
            float v = acc[i][n] + bv[n];
            if (EPI == 1) v = 0.5f * v * (1.f + erff(v * 0.70710678118654752440f));
            dst[m * 192 + ocb + n] = v;
        }
    }
}

// ---- fused window attention: block = (bb, t, m); 6 waves = 6 heads; lane = query
__global__ __launch_bounds__(384, 1)
void winattn_kernel(const float* __restrict__ qbuf, const float* __restrict__ kbuf,
                    const float* __restrict__ vbuf, const float* __restrict__ mask,
                    const float* __restrict__ rpbt, float* __restrict__ xp)
{
    __shared__ float klds[64 * 192];
    __shared__ float vlds[64 * 192];
    __shared__ float mlds[64 * 65];   // +1 pad: conflict-free lane-major reads
    __shared__ float rlds[1350];
    const int tid = threadIdx.x;
    const int bid = blockIdx.x;       // bb*16 + t*4 + m
    const int bb = bid >> 4;
    const int t = (bid >> 2) & 3;
    const int m = bid & 3;
    const int h = tid >> 6;
    const int lane = tid & 63;

    const int kvbase = (bb * 4 + m) * 12288;
#pragma unroll
    for (int j = 0; j < 8; j++) {
        int off = (tid + j * 384) * 4;
        *reinterpret_cast<float4*>(&klds[off]) =
            *reinterpret_cast<const float4*>(&kbuf[kvbase + off]);
        *reinterpret_cast<float4*>(&vlds[off]) =
            *reinterpret_cast<const float4*>(&vbuf[kvbase + off]);
    }
    const int widx = bb & 63;
    for (int f = tid; f < 4096; f += 384)
        mlds[(f >> 6) * 65 + (f & 63)] = mask[widx * 4096 + f];
    for (int f = tid; f < 1350; f += 384) rlds[f] = rpbt[f];

    float qreg[32];
    const int qbase = ((bb * 4 + t) * 64 + lane) * 192 + h * 32;
#pragma unroll
    for (int j = 0; j < 8; j++) {
        float4 v = *reinterpret_cast<const float4*>(&qbuf[qbase + j * 4]);
        qreg[4 * j] = v.x; qreg[4 * j + 1] = v.y;
        qreg[4 * j + 2] = v.z; qreg[4 * j + 3] = v.w;
    }
    __syncthreads();

    const float scale = 0.17677669529663688110f;  // 1/sqrt(32)
    const int ni = lane >> 3, nj = lane & 7;
    float s[64];
#pragma unroll
    for (int e = 0; e < 64; e++) {
        const float4* kr = reinterpret_cast<const float4*>(&klds[e * 192 + h * 32]);
        float d0 = 0, d1 = 0, d2 = 0, d3 = 0;
#pragma unroll
        for (int q8 = 0; q8 < 8; q8++) {
            float4 k4 = kr[q8];
            d0 += qreg[q8 * 4] * k4.x;
            d1 += qreg[q8 * 4 + 1] * k4.y;
            d2 += qreg[q8 * 4 + 2] * k4.z;
            d3 += qreg[q8 * 4 + 3] * k4.w;
        }
        // relative position bias index, computed analytically (WIN = 8x8)
        int ridx = (ni - (e >> 3) + 7) * 15 + (nj - (e & 7) + 7);
        s[e] = (d0 + d1 + d2 + d3) * scale + rlds[ridx * 6 + h] + mlds[lane * 65 + e];
    }
    float mx = s[0];
#pragma unroll
    for (int e = 1; e < 64; e++) mx = fmaxf(mx, s[e]);
    float l = 0.f;
#pragma unroll
    for (int e = 0; e < 64; e++) { s[e] = __expf(s[e] - mx); l += s[e]; }
    const float inv = 1.f / l;

    float o[32];
#pragma unroll
    for (int d = 0; d < 32; d++) o[d] = 0.f;
#pragma unroll
    for (int e = 0; e < 64; e++) {
        float p = s[e];
        const float4* vr = reinterpret_cast<const float4*>(&vlds[e * 192 + h * 32]);
#pragma unroll
        for (int d8 = 0; d8 < 8; d8++) {
            float4 v4 = vr[d8];
            o[d8 * 4] += p * v4.x; o[d8 * 4 + 1] += p * v4.y;
            o[d8 * 4 + 2] += p * v4.z; o[d8 * 4 + 3] += p * v4.w;
        }
    }
    // faithful-torch scrambled xp layout: t' = m, m' = t, (h,n,d) reinterleaved
    const int obase = bb * 196608 + m * 49152 + t * 12288 + h * 2048 + lane * 32;
#pragma unroll
    for (int j = 0; j < 8; j++) {
        float4 v;
        v.x = o[4 * j] * inv; v.y = o[4 * j + 1] * inv;
        v.z = o[4 * j + 2] * inv; v.w = o[4 * j + 3] * inv;
        *reinterpret_cast<float4*>(&xp[obase + j * 4]) = v;
    }
}

// ---- t0[bt,n,c] = mean_m xp[bt,m,n,c] + pos_emb[n,c]  (qq GEMM input)
__global__ void avgtok_kernel(const float* __restrict__ xp, const float* __restrict__ pos,
                              float* __restrict__ t0)
{
    int i4 = blockIdx.x * blockDim.x + threadIdx.x;
    if (i4 >= 512 * 64 * 48) return;
    int c = (i4 % 48) * 4;
    int n = (i4 / 48) & 63;
    int bt = i4 / (48 * 64);
    int base = bt * 49152 + n * 192 + c;
    float4 a = *reinterpret_cast<const float4*>(&xp[base]);
    float4 b = *reinterpret_cast<const float4*>(&xp[base + 12288]);
    float4 cc = *reinterpret_cast<const float4*>(&xp[base + 24576]);
    float4 d = *reinterpret_cast<const float4*>(&xp[base + 36864]);
    float4 p = *reinterpret_cast<const float4*>(&pos[n * 192 + c]);
    float4 o;
    o.x = 0.25f * (a.x + b.x + cc.x + d.x) + p.x;
    o.y = 0.25f * (a.y + b.y + cc.y + d.y) + p.y;
    o.z = 0.25f * (a.z + b.z + cc.z + d.z) + p.z;
    o.w = 0.25f * (a.w + b.w + cc.w + d.w) + p.w;
    *reinterpret_cast<float4*>(&t0[bt * 12288 + n * 192 + c]) = o;
}

// ---- pooling attention: block = bt; flash over 10 key tiles of 32 tokens.
// K/V projections computed on the fly in LDS (saves 252 MB of workspace).
__global__ __launch_bounds__(384, 3)
void poolattn_kernel(const float* __restrict__ xp, const float* __restrict__ pos,
                     const float* __restrict__ qq,
                     const float* __restrict__ pkT, const float* __restrict__ pkb,
                     const float* __restrict__ pvT, const float* __restrict__ pvb,
                     float* __restrict__ opool)
{
    __shared__ float tok[32 * 192];
    __shared__ float kls[32 * 192];
    __shared__ float vls[32 * 192];
    const int tid = threadIdx.x;
    const int bt = blockIdx.x;
    const int h = tid >> 6, lane = tid & 63;
    const int oc = tid % 192;     // projection-phase mapping
    const int jh = tid / 192;     // 0 or 1 (16-token half)

    float qreg[32];
    const int qbase = (bt * 64 + lane) * 192 + h * 32;
#pragma unroll
    for (int j = 0; j < 8; j++) {
        float4 v = *reinterpret_cast<const float4*>(&qq[qbase + j * 4]);
        qreg[4 * j] = v.x; qreg[4 * j + 1] = v.y;
        qreg[4 * j + 2] = v.z; qreg[4 * j + 3] = v.w;
    }
    const float scale = 0.17677669529663688110f;
    float mrun = -3.0e38f, lrun = 0.f;
    float o[32];
#pragma unroll
    for (int d = 0; d < 32; d++) o[d] = 0.f;

    for (int tt = 0; tt < 10; tt++) {
        const int mIdx = tt >> 1;           // 0 = avg tokens
        const int nbase = (tt & 1) * 32;
        __syncthreads();
        // build token tile (avg or xp slice, + pos_emb)
        for (int f = tid; f < 6144; f += 384) {
            int j = f / 192, c = f - j * 192;
            int n = nbase + j;
            float v;
            if (mIdx == 0) {
                int xb = bt * 49152 + n * 192 + c;
                v = 0.25f * (xp[xb] + xp[xb + 12288] + xp[xb + 24576] + xp[xb + 36864]);
            } else {
                v = xp[bt * 49152 + (mIdx - 1) * 12288 + n * 192 + c];
            }
            tok[f] = v + pos[n * 192 + c];
        }
        __syncthreads();
        // project tile through pk / pv into LDS
        {
            float accK[16], accV[16];
#pragma unroll
            for (int j = 0; j < 16; j++) { accK[j] = 0.f; accV[j] = 0.f; }
            const float* trow = &tok[jh * 16 * 192];
            for (int ic = 0; ic < 192; ic += 4) {
                float wk0 = pkT[ic * 192 + oc];
                float wk1 = pkT[(ic + 1) * 192 + oc];
                float wk2 = pkT[(ic + 2) * 192 + oc];
                float wk3 = pkT[(ic + 3) * 192 + oc];
                float wv0 = pvT[ic * 192 + oc];
                float wv1 = pvT[(ic + 1) * 192 + oc];
                float wv2 = pvT[(ic + 2) * 192 + oc];
                float wv3 = pvT[(ic + 3) * 192 + oc];
#pragma unroll
                for (int j = 0; j < 16; j++) {
                    float4 tv = *reinterpret_cast<const float4*>(&trow[j * 192 + ic]);
                    accK[j] += tv.x * wk0 + tv.y * wk1 + tv.z * wk2 + tv.w * wk3;
                    accV[j] += tv.x * wv0 + tv.y * wv1 + tv.z * wv2 + tv.w * wv3;
                }
            }
            float kb = pkb[oc], vb = pvb[oc];
#pragma unroll
            for (int j = 0; j < 16; j++) {
                kls[(jh * 16 + j) * 192 + oc] = accK[j] + kb;
                vls[(jh * 16 + j) * 192 + oc] = accV[j] + vb;
            }
        }
        __syncthreads();
        // flash-attention update over this 32-key tile (all lane-local)
        float s[32];
#pragma unroll
        for (int j = 0; j < 32; j++) {
            const float4* kr = reinterpret_cast<const float4*>(&kls[j * 192 + h * 32]);
            float d0 = 0, d1 = 0, d2 = 0, d3 = 0;
#pragma unroll
            for (int q8 = 0; q8 < 8; q8++) {
                float4 k4 = kr[q8];
                d0 += qreg[q8 * 4] * k4.x;
                d1 += qreg[q8 * 4 + 1] * k4.y;
                d2 += qreg[q8 * 4 + 2] * k4.z;
                d3 += qreg[q8 * 4 + 3] * k4.w;
            }
            s[j] = (d0 + d1 + d2 + d3) * scale;
        }
        float mt = s[0];
#pragma unroll
        for (int j = 1; j < 32; j++) mt = fmaxf(mt, s[j]);
        float mnew = fmaxf(mrun, mt);
        float fct = __expf(mrun - mnew);   // first iter: exp(-huge) = 0
        lrun *= fct;
#pragma unroll
        for (int d = 0; d < 32; d++) o[d] *= fct;
#pragma unroll
        for (int j = 0; j < 32; j++) { float p = __expf(s[j] - mnew); lrun += p; s[j] = p; }
#pragma unroll
        for (int j = 0; j < 32; j++) {
            float p = s[j];
            const float4* vr = reinterpret_cast<const float4*>(&vls[j * 192 + h * 32]);
#pragma unroll
            for (int d8 = 0; d8 < 8; d8++) {
                float4 v4 = vr[d8];
                o[d8 * 4] += p * v4.x; o[d8 * 4 + 1] += p * v4.y;
                o[d8 * 4 + 2] += p * v4.z; o[d8 * 4 + 3] += p * v4.w;
            }
        }
        mrun = mnew;
    }
    const float inv = 1.f / lrun;
    const int obase = (bt * 64 + lane) * 192 + h * 32;
#pragma unroll
    for (int j = 0; j < 8; j++) {
        float4 v;
        v.x = o[4 * j] * inv; v.y = o[4 * j + 1] * inv;
        v.z = o[4 * j + 2] * inv; v.w = o[4 * j + 3] * inv;
        *reinterpret_cast<float4*>(&opool[obase + j * 4]) = v;
    }
}

extern "C" void kernel_launch(void* const* d_in, const int* in_sizes, int n_in,
                              void* d_out, int out_size, void* d_ws, size_t ws_size,
                              hipStream_t stream) {
    (void)in_sizes; (void)n_in; (void)out_size; (void)ws_size;
    const float* x      = (const float*)d_in[0];
    const float* x_kv   = (const float*)d_in[1];
    const float* mask   = (const float*)d_in[2];
    const float* rpbt   = (const float*)d_in[3];
    const float* q_w    = (const float*)d_in[4];
    const float* q_b    = (const float*)d_in[5];
    const float* kv_w   = (const float*)d_in[6];
    const float* kv_b   = (const float*)d_in[7];
    const float* pos    = (const float*)d_in[8];
    const float* pq_w   = (const float*)d_in[9];
    const float* pq_b   = (const float*)d_in[10];
    const float* pk_w   = (const float*)d_in[11];
    const float* pk_b   = (const float*)d_in[12];
    const float* pv_w   = (const float*)d_in[13];
    const float* pv_b   = (const float*)d_in[14];
    const float* po_w   = (const float*)d_in[15];
    const float* po_b   = (const float*)d_in[16];
    const float* proj_w = (const float*)d_in[17];
    const float* proj_b = (const float*)d_in[18];
    float* out = (float*)d_out;
    char* ws = (char*)d_ws;

    float* wqT  = (float*)(ws + 0);
    float* wkvT = (float*)(ws + 147456);
    float* wpqT = (float*)(ws + 442368);
    float* wpkT = (float*)(ws + 589824);
    float* wpvT = (float*)(ws + 737280);
    float* wpoT = (float*)(ws + 884736);
    float* wprT = (float*)(ws + 1032192);
    const size_t A0 = 1179648;
    float* qbuf = (float*)(ws + A0);
    float* kbuf = (float*)(ws + A0 + 25165824u);
    float* vbuf = (float*)(ws + A0 + 2u * 25165824u);
    float* xp   = (float*)(ws + A0 + 3u * 25165824u);
    // reuse after window attention:
    float* t0 = qbuf;
    float* qq = kbuf;
    float* opool = vbuf;
    float* opo = qbuf;

    wt_kernel<<<(192 * 192 + 255) / 256, 256, 0, stream>>>(q_w, wqT, 192);
    wt_kernel<<<(384 * 192 + 255) / 256, 256, 0, stream>>>(kv_w, wkvT, 384);
    wt_kernel<<<(192 * 192 + 255) / 256, 256, 0, stream>>>(pq_w, wpqT, 192);
    wt_kernel<<<(192 * 192 + 255) / 256, 256, 0, stream>>>(pk_w, wpkT, 192);
    wt_kernel<<<(192 * 192 + 255) / 256, 256, 0, stream>>>(pv_w, wpvT, 192);
    wt_kernel<<<(192 * 192 + 255) / 256, 256, 0, stream>>>(po_w, wpoT, 192);
    wt_kernel<<<(192 * 192 + 255) / 256, 256, 0, stream>>>(proj_w, wprT, 192);

    dim3 g2(256, 2), g4(256, 4), blk(256);
    gemm_kernel<0><<<g2, blk, 0, stream>>>(x, wqT, q_b, qbuf, nullptr, 192);
    gemm_kernel<2><<<g4, blk, 0, stream>>>(x_kv, wkvT, kv_b, kbuf, vbuf, 384);
    winattn_kernel<<<2048, 384, 0, stream>>>(qbuf, kbuf, vbuf, mask, rpbt, xp);
    avgtok_kernel<<<6144, 256, 0, stream>>>(xp, pos, t0);
    gemm_kernel<0><<<g2, blk, 0, stream>>>(t0, wpqT, pq_b, qq, nullptr, 192);
    poolattn_kernel<<<512, 384, 0, stream>>>(xp, pos, qq, wpkT, pk_b, wpvT, pv_b, opool);
    gemm_kernel<1><<<g2, blk, 0, stream>>>(opool, wpoT, po_b, opo, nullptr, 192);
    gemm_kernel<0><<<g2, blk, 0, stream>>>(opo, wprT, proj_b, out, nullptr, 192);
}